// Round 1
// 467.047 us; speedup vs baseline: 1.0413x; 1.0413x over previous
//
#include <hip/hip_runtime.h>

// aer_feat: (B=4, C=64, HA=512, WA=512) f32
// pose_uvr: (B=4, N=256, 3) f32
// out:      (B, N, C, HB=32, WB=32) f32
constexpr int HB_ = 32, WB_ = 32;
constexpr int HA_ = 512, WA_ = 512;
constexpr int C_  = 64,  N_  = 256;

// Staged window: rotated 32x32 patch spans <= 31*sqrt(2) ~= 43.85 px,
// + bilinear +1 + rounding guard (x_lo -= 1). 48 rows cover y; cols are
// widened to 52 with the origin aligned down to a 16B boundary (x_lo & ~3,
// slack <= 3; 3 + 48 <= 51 < 52) so each row is 13 aligned float4 groups.
constexpr int SH    = 48;             // staged rows
constexpr int SCOLS = 52;             // staged cols
constexpr int SW    = SCOLS;          // LDS row stride — MUST stay unpadded:
                                      // global_load_lds needs slot index linear
constexpr int GPROW = SCOLS / 4;      // 13 float4 groups per row
constexpr int NGRP  = SH * GPROW;     // 624 groups per plane (= 256*2 + 112)
constexpr int PLANE = SH * SW;        // 2496 floats = 9984 B per channel plane
constexpr int CPR   = 4;              // channels per barrier round

typedef float f4v __attribute__((ext_vector_type(4)));

__global__ __launch_bounds__(256, 4) void aps_kernel(
    const float* __restrict__ aer, const float* __restrict__ pose,
    float* __restrict__ out)
{
    __shared__ float lds[CPR * PLANE];   // 39,936 B -> 4 blocks/CU

    const int bn  = blockIdx.x;          // b*N + n
    const int b   = bn >> 8;             // N = 256
    const int tid = threadIdx.x;

    const float u  = pose[bn * 3 + 0];
    const float v  = pose[bn * 3 + 1];
    const float th = pose[bn * 3 + 2];
    float s_r, c_r;
    sincosf(-th, &s_r, &c_r);            // sin(-theta), cos(-theta)

    // ---- bounding box of the rotated patch (wave-uniform) ----
    const float a00 = -s_r * -16.0f,              a01 = -s_r * 15.0f;
    const float a10 = c_r * 31.0f - s_r * -16.0f, a11 = c_r * 31.0f - s_r * 15.0f;
    const float gumin = u + fminf(fminf(a00, a01), fminf(a10, a11));
    const float b00 = c_r * -16.0f,               b01 = c_r * 15.0f;
    const float b10 = s_r * 31.0f + c_r * -16.0f, b11 = s_r * 31.0f + c_r * 15.0f;
    const float gvmin = v + fminf(fminf(b00, b01), fminf(b10, b11));
    const int x_lo  = (int)floorf(gumin) - 1;   // -1: rounding guard vs ref chain
    const int y_lo  = (int)floorf(gvmin) - 1;
    const int x_lo4 = x_lo & ~3;                // 16B-aligned staging origin

    // ---- per-thread staging source offsets (one float4 group per slot) ----
    // Mask-free: any tap that could touch an OOB staged slot already has an
    // exactly-zero weight (image-bounds validity is in w[k][*]), so staged
    // garbage from a clamped address is inert. Groups are all-in/all-out in x
    // because x_lo4 and WA are multiples of 4.
    int goff[3];
    #pragma unroll
    for (int k = 0; k < 3; ++k) {
        const int g  = tid + 256 * k;
        const int r  = g / GPROW;
        const int c4 = g - r * GPROW;
        const int y  = y_lo + r;
        const int x  = x_lo4 + c4 * 4;
        const bool ok = ((unsigned)y < (unsigned)HA_) && ((unsigned)x < (unsigned)WA_);
        goff[k] = ok ? (y * WA_ + x) : 0;
    }

    // ---- per-position taps (LDS-relative), exact ref arithmetic ----
    const int i  = tid >> 3;             // patch row hb
    const int j0 = (tid & 7) * 4;        // first of 4 patch cols
    const float gu_i = u + c_r * (float)(HB_ - 1 - i);
    const float gv_i = v + s_r * (float)(HB_ - 1 - i);

    int   lbase[4];
    float w[4][4];
    #pragma unroll
    for (int k = 0; k < 4; ++k) {
        const float gv0 = (float)(j0 + k - WB_ / 2);
        const float gu  = gu_i - s_r * gv0;
        const float gv  = gv_i + c_r * gv0;
        float gx = (gu + 0.5f) * (2.0f / (float)WA_) - 1.0f;
        float gy = (gv + 0.5f) * (2.0f / (float)HA_) - 1.0f;
        const bool valid = (fabsf(gx) < 1.0f) && (fabsf(gy) < 1.0f);
        if (!valid) { gx = 2.0f; gy = 2.0f; }
        const float ix = ((gx + 1.0f) * (float)WA_ - 1.0f) * 0.5f;
        const float iy = ((gy + 1.0f) * (float)HA_ - 1.0f) * 0.5f;
        const float x0f = floorf(ix), y0f = floorf(iy);
        const float wx1 = ix - x0f, wx0 = 1.0f - wx1;
        const float wy1 = iy - y0f, wy0 = 1.0f - wy1;
        const int x0 = (int)x0f, y0 = (int)y0f;
        const int x1 = x0 + 1,   y1 = y0 + 1;
        const bool vx0 = (x0 >= 0) & (x0 < WA_);
        const bool vx1 = (x1 >= 0) & (x1 < WA_);
        const bool vy0 = (y0 >= 0) & (y0 < HA_);
        const bool vy1 = (y1 >= 0) & (y1 < HA_);
        w[k][0] = wx0 * wy0 * ((vx0 && vy0) ? 1.0f : 0.0f);
        w[k][1] = wx1 * wy0 * ((vx1 && vy0) ? 1.0f : 0.0f);
        w[k][2] = wx0 * wy1 * ((vx0 && vy1) ? 1.0f : 0.0f);
        w[k][3] = wx1 * wy1 * ((vx1 && vy1) ? 1.0f : 0.0f);
        // LDS-relative tap origin; clamp keeps +1/+SW/+SW+1 inside the staged
        // area (only zero-weight taps ever hit the clamp — see bbox margins)
        const int lx = min(max(x0 - x_lo4, 0), SCOLS - 2);
        const int ly = min(max(y0 - y_lo, 0), SH - 2);
        lbase[k] = ly * SW + lx;
    }

    const float* img = aer + (size_t)b * C_ * (HA_ * WA_);
    float* op = out + (size_t)bn * C_ * (HB_ * WB_) + tid * 4;

    for (int c0 = 0; c0 < C_; c0 += CPR) {
        __syncthreads();   // previous round's reads done before overwrite
        #pragma unroll
        for (int cc = 0; cc < CPR; ++cc) {
            const float* im = img + (size_t)(c0 + cc) * (HA_ * WA_);
            float* pl = &lds[cc * PLANE];
            // async global->LDS DMA, 16B per lane; LDS slot index == group
            // index (13 groups/row * 48 rows, stride unpadded), so the
            // wave-uniform-base + lane*16 destination rule is satisfied.
            __builtin_amdgcn_global_load_lds(
                (const __attribute__((address_space(1))) unsigned int*)(im + goff[0]),
                (__attribute__((address_space(3))) unsigned int*)(pl + tid * 4),
                16, 0, 0);
            __builtin_amdgcn_global_load_lds(
                (const __attribute__((address_space(1))) unsigned int*)(im + goff[1]),
                (__attribute__((address_space(3))) unsigned int*)(pl + (tid + 256) * 4),
                16, 0, 0);
            if (tid < NGRP - 512) {   // 112 tail groups
                __builtin_amdgcn_global_load_lds(
                    (const __attribute__((address_space(1))) unsigned int*)(im + goff[2]),
                    (__attribute__((address_space(3))) unsigned int*)(pl + (tid + 512) * 4),
                    16, 0, 0);
            }
        }
        __syncthreads();   // compiler inserts vmcnt(0) before the barrier
        #pragma unroll
        for (int cc = 0; cc < CPR; ++cc) {
            const float* p = &lds[cc * PLANE];
            float rr[4];
            #pragma unroll
            for (int k = 0; k < 4; ++k) {
                const int lb = lbase[k];
                rr[k] = w[k][0] * p[lb]      + w[k][1] * p[lb + 1]
                      + w[k][2] * p[lb + SW] + w[k][3] * p[lb + SW + 1];
            }
            f4v r4 = {rr[0], rr[1], rr[2], rr[3]};
            // nontemporal: output is write-once — keep it out of L2/L3 so the
            // input image stays resident (input+output > 256MB L3 otherwise)
            __builtin_nontemporal_store(r4,
                (f4v*)(op + (size_t)(c0 + cc) * (HB_ * WB_)));
        }
    }
}

extern "C" void kernel_launch(void* const* d_in, const int* in_sizes, int n_in,
                              void* d_out, int out_size, void* d_ws, size_t ws_size,
                              hipStream_t stream) {
    const float* aer  = (const float*)d_in[0];   // (4,64,512,512) f32
    const float* pose = (const float*)d_in[1];   // (4,256,3) f32
    float* out = (float*)d_out;                  // (4,256,64,32,32) f32
    const int B = 4;
    aps_kernel<<<dim3(B * N_), dim3(256), 0, stream>>>(aer, pose, out);
}